// Round 5
// baseline (508.442 us; speedup 1.0000x reference)
//
#include <hip/hip_runtime.h>
#include <hip/hip_bf16.h>

typedef __hip_bfloat16 bf16;
typedef __attribute__((ext_vector_type(8))) short bf16x8v;   // 8 bf16 (4 VGPRs) MFMA operand
typedef __attribute__((ext_vector_type(4))) float f32x4;     // MFMA accumulator
typedef __attribute__((ext_vector_type(4))) short short4v;   // 8B packed bf16 store

#define B_SZ   2048
#define NSTEP  128
#define DD     100
#define DX     100
#define DH     256

#define UCOLS  104          // 100 x-dims + t + 3 zero pad (global U layout)

__device__ __constant__ const float DT_   = 0.0078125f;              // 1/128
__device__ __constant__ const float SQDT_ = 0.08838834764831845f;    // sqrt(1/128)
// sqrt(2)*sqrt(dt) = sqrt(2/128) = 1/8 exactly
__device__ __constant__ const float C1_   = 0.125f;

// ---------------------------------------------------------------------------
// Kernel 1: per-batch prefix sums of noise -> build U rows (bf16) + final x
// U row p = (b*128 + i)*2 + h ; cols 0..99 = x-part, col 100 = t, 101..103 = 0
// ---------------------------------------------------------------------------
__global__ __launch_bounds__(128) void prep_kernel(
    const float* __restrict__ Wn, const int* __restrict__ signs,
    const float* __restrict__ x0,
    bf16* __restrict__ U, float* __restrict__ xout)
{
    __shared__ float w_l[DD * 129];   // padded stride 129 -> conflict-free
    __shared__ float s_l[NSTEP];
    const int b = blockIdx.x, tid = threadIdx.x;
    const float* wb = Wn + (size_t)b * DD * NSTEP;

    for (int idx = tid; idx < DD * NSTEP; idx += 128) {
        int d = idx >> 7, i = idx & 127;
        w_l[d * 129 + i] = wb[idx];
    }
    if (tid < NSTEP) s_l[tid] = 2.f * (float)signs[tid] - 1.f;
    __syncthreads();

    if (tid < DD) {
        const int d = tid;
        float x = x0[d];
        for (int i = 0; i < NSTEP; ++i) {
            size_t p = ((size_t)(b * NSTEP + i)) * 2;
            float wn = w_l[d * 129 + i];
            U[p * UCOLS + d]       = __float2bfloat16(x);
            U[(p + 1) * UCOLS + d] = __float2bfloat16(x + C1_ * (wn - s_l[i]));
            x += C1_ * wn;
        }
        xout[(size_t)b * DX + d] = x;   // exact f32 final x
    } else if (tid < UCOLS) {
        for (int i = 0; i < NSTEP; ++i) {
            size_t p = ((size_t)(b * NSTEP + i)) * 2;
            float v0 = 0.f, v1 = 0.f;
            if (tid == 100) { v0 = DT_ * (float)i; v1 = DT_ * (float)(i + 1); }
            U[p * UCOLS + tid]       = __float2bfloat16(v0);
            U[(p + 1) * UCOLS + tid] = __float2bfloat16(v1);
        }
    }
}

// ---------------------------------------------------------------------------
// Weight fragment packing: W[Kact][Nact] f32 -> bf16 A-frags of W^T, C-MAJOR:
// frag# = c*NTILE + t  (all n-tiles of one k-chunk contiguous -> per-c a-loads
// span one compact 16KB window). elem idx = frag#*512 + lane*8 + j.
// n = t*16+(lane&15), k = c*32+(lane>>4)*8+j. OOR -> 0.
// ---------------------------------------------------------------------------
__global__ __launch_bounds__(256) void wpack_kernel(
    const float* __restrict__ W, bf16* __restrict__ dst,
    int Kact, int Nact, int NTILE, int total)
{
    int idx = blockIdx.x * 256 + threadIdx.x;
    if (idx >= total) return;
    int j = idx & 7;
    int l = (idx >> 3) & 63;
    int frag = idx >> 9;
    int t = frag % NTILE;
    int c = frag / NTILE;
    int n = t * 16 + (l & 15);
    int k = c * 32 + (l >> 4) * 8 + j;
    float v = (k < Kact && n < Nact) ? W[(size_t)k * Nact + n] : 0.f;
    dst[idx] = __float2bfloat16(v);
}

// Pack biases into one padded f32 buffer: [0:256)=bi [256:512)=bh1 [512:768)=bh2 [768:896)=bo(pad0)
__global__ __launch_bounds__(256) void bpack_kernel(
    const float* __restrict__ bi, const float* __restrict__ bh1,
    const float* __restrict__ bh2, const float* __restrict__ bo,
    float* __restrict__ dst)
{
    int i = blockIdx.x * 256 + threadIdx.x;
    if (i < 256) dst[i] = bi[i];
    else if (i < 512) dst[i] = bh1[i - 256];
    else if (i < 768) dst[i] = bh2[i - 512];
    else if (i < 896) dst[i] = (i - 768 < DD) ? bo[i - 768] : 0.f;
}

// ---------------------------------------------------------------------------
// One MFMA layer, WAVE-PRIVATE: the wave owns 32 rows [m0, m0+32) and computes
// ALL NTILE*16 output features for them. No inter-wave data sharing -> no
// barrier needed for correctness (in-place read->write is same-wave, ordered
// by lgkmcnt). Act-LDS traffic is 1x (vs 4x when waves split features).
// acc[NTILE][2] = NTILE*8 VGPRs (128 for NTILE=16).
// a-frags: one load per (c,t), c-major layout -> 16KB window per c.
// #pragma unroll 2 on c bounds register pressure (R3/R4 spill lesson).
// ---------------------------------------------------------------------------
template<int KC, int NTILE, bool RELU>
__device__ __forceinline__ void layer_wave(
    char* __restrict__ buf,
    const bf16* __restrict__ wfrag, const float* __restrict__ bias,
    int lane, int m0)
{
    const int lrow = lane & 15;   // m_local (B col) / n_local (A row)
    const int lkg  = lane >> 4;   // k-group
    f32x4 acc[NTILE][2];
#pragma unroll
    for (int t = 0; t < NTILE; ++t) {
        acc[t][0] = (f32x4){0.f, 0.f, 0.f, 0.f};
        acc[t][1] = (f32x4){0.f, 0.f, 0.f, 0.f};
    }

    const char* wptr = (const char*)wfrag + (size_t)lane * 16;

#pragma unroll 2
    for (int c = 0; c < KC; ++c) {
        const int ma = m0 + lrow;
        const int mb = m0 + 16 + lrow;
        bf16x8v b0 = *(const bf16x8v*)(buf + ma * 512 +
                                       ((c * 64 + lkg * 16) ^ ((ma & 7) << 4)));
        bf16x8v b1 = *(const bf16x8v*)(buf + mb * 512 +
                                       ((c * 64 + lkg * 16) ^ ((mb & 7) << 4)));
        __builtin_amdgcn_s_setprio(1);
#pragma unroll
        for (int t = 0; t < NTILE; ++t) {
            bf16x8v a = *(const bf16x8v*)(wptr + (size_t)(c * NTILE + t) * 1024);
            acc[t][0] = __builtin_amdgcn_mfma_f32_16x16x32_bf16(a, b0, acc[t][0], 0, 0, 0);
            acc[t][1] = __builtin_amdgcn_mfma_f32_16x16x32_bf16(a, b1, acc[t][1], 0, 0, 0);
        }
        __builtin_amdgcn_s_setprio(0);
    }

    // Epilogue: bias+relu+pack, write back IN PLACE to the wave's own rows.
    // Same-wave LDS read->write ordering handled by waitcnt; no barrier.
#pragma unroll
    for (int t = 0; t < NTILE; ++t) {
        const int nb = t * 16 + lkg * 4;   // first of 4 consecutive features
        const float4 bv = *(const float4*)(bias + nb);
#pragma unroll
        for (int mt = 0; mt < 2; ++mt) {
            const int m = m0 + mt * 16 + lrow;
            float v0 = acc[t][mt][0] + bv.x;
            float v1 = acc[t][mt][1] + bv.y;
            float v2 = acc[t][mt][2] + bv.z;
            float v3 = acc[t][mt][3] + bv.w;
            if (RELU) {
                v0 = fmaxf(v0, 0.f); v1 = fmaxf(v1, 0.f);
                v2 = fmaxf(v2, 0.f); v3 = fmaxf(v3, 0.f);
            }
            bf16 h0 = __float2bfloat16(v0), h1 = __float2bfloat16(v1);
            bf16 h2 = __float2bfloat16(v2), h3 = __float2bfloat16(v3);
            short4v pv;
            pv[0] = *(short*)&h0; pv[1] = *(short*)&h1;
            pv[2] = *(short*)&h2; pv[3] = *(short*)&h3;
            *(short4v*)(buf + m * 512 + ((nb * 2) ^ ((m & 7) << 4))) = pv;
        }
    }
}

// ---------------------------------------------------------------------------
// Kernel 2: fused 4-layer MFMA MLP over 128 rows + per-pair y-increment.
// 4 waves, PURE m-split: wave w owns rows [w*32, w*32+32) and computes all
// features each layer. Waves are fully independent; the per-layer
// __syncthreads are ONLY to convoy waves through the shared weight stream
// (L1 reuse), not for correctness. buf [128][512B], swizzled. LDS 64KB ->
// 2 blocks/CU. acc 128 AGPR + ~60 arch VGPR -> no spill (watch WRITE_SIZE).
// ---------------------------------------------------------------------------
__global__ __launch_bounds__(256, 2) void mlp_mfma_kernel(
    const bf16* __restrict__ U,
    const float* __restrict__ Wn, const int* __restrict__ signs,
    const bf16* __restrict__ wfWi, const bf16* __restrict__ wfWh1,
    const bf16* __restrict__ wfWh2, const bf16* __restrict__ wfWo,
    const float* __restrict__ biases, float* __restrict__ incr)
{
    __shared__ char buf[128 * 512];
    const int tid = threadIdx.x;
    const int lane = tid & 63, w = tid >> 6;
    const int m0 = w * 32;
    const size_t row0 = (size_t)blockIdx.x * 128;

    // Per-wave staging of its OWN 32 rows: 104 bf16 = 13 x 16B chunks/row into
    // buf rows [m0, m0+32) stride 512B, swizzled; chunks 13..15 zero-filled
    // (k padding must be 0). Layer-1 input spans bytes 0..255 of each row.
    {
        const char* usrc = (const char*)(U + (row0 + m0) * UCOLS);
#pragma unroll
        for (int it = 0; it < 8; ++it) {
            int idx = it * 64 + lane;
            int r = idx >> 4, c = idx & 15;
            uint4 v = (uint4){0, 0, 0, 0};
            if (c < 13) v = *(const uint4*)(usrc + r * 208 + c * 16);
            int m = m0 + r;
            *(uint4*)(buf + m * 512 + ((c * 16) ^ ((m & 7) << 4))) = v;
        }
    }
    __syncthreads();   // convoy only

    layer_wave<4, 16, true >(buf, wfWi,  biases,        lane, m0);
    __syncthreads();   // convoy only
    layer_wave<8, 16, true >(buf, wfWh1, biases + 256,  lane, m0);
    __syncthreads();   // convoy only
    layer_wave<8, 16, true >(buf, wfWh2, biases + 512,  lane, m0);
    __syncthreads();   // convoy only
    layer_wave<8, 8,  false>(buf, wfWo,  biases + 768,  lane, m0);
    // z rows for this wave now in buf rows [m0, m0+32), features 0..99 valid.

    // Per-wave reduction: 2 lanes per row (q = lane&1), rows r = lane>>1.
    {
        const int q = lane & 1;
        const int r = lane >> 1;              // 0..31 local
        const int m = m0 + r;                 // buffer row
        const size_t g = row0 + m;            // global row
        const size_t pair = g >> 1;
        const int h = (int)(g & 1);
        const int bb = (int)(pair >> 7), ii = (int)(pair & 127);
        const float s = 2.f * (float)signs[ii] - 1.f;
        const float sdt = s * SQDT_;
        const float* wb = Wn + (size_t)bb * DD * NSTEP + ii;

        float sz2 = 0.f, szw = 0.f;
        for (int d = q; d < DD; d += 2) {
            unsigned short zb = *(const unsigned short*)(buf + m * 512 + ((d * 2) ^ ((m & 7) << 4)));
            union { unsigned int u; float f; } cv; cv.u = ((unsigned int)zb) << 16;
            float z = cv.f;
            float wv = SQDT_ * wb[(size_t)d * NSTEP];
            float wt = h ? (wv + sdt) : (wv - sdt);
            sz2 += z * z;
            szw += z * wt;
        }
        sz2 += __shfl_xor(sz2, 1);            // full row sums on both lanes
        szw += __shfl_xor(szw, 1);
        float szw_o = __shfl_xor(szw, 2);     // partner (odd) row's szw
        // incr = -||z||^2*dt + 0.5*(z.(w-sdt) + z_new.(w+sdt)); z from h=0 row
        if ((lane & 3) == 0) {                // r even -> h=0 row, sz2 is correct z
            incr[row0 / 2 + w * 16 + (lane >> 2)] =
                -sz2 * DT_ + 0.5f * (szw + szw_o);
        }
    }
}

// ---------------------------------------------------------------------------
// Kernel 3: y[b] = y0 + sum_i incr[b*128+i]
// ---------------------------------------------------------------------------
__global__ __launch_bounds__(128) void y_kernel(
    const float* __restrict__ incr, const float* __restrict__ y0,
    float* __restrict__ yout)
{
    const int b = blockIdx.x, tid = threadIdx.x;
    float v = incr[(size_t)b * NSTEP + tid];
#pragma unroll
    for (int off = 1; off < 64; off <<= 1) v += __shfl_xor(v, off);
    __shared__ float partial[2];
    if ((tid & 63) == 0) partial[tid >> 6] = v;
    __syncthreads();
    if (tid == 0) yout[b] = y0[0] + partial[0] + partial[1];
}

// ---------------------------------------------------------------------------
extern "C" void kernel_launch(void* const* d_in, const int* in_sizes, int n_in,
                              void* d_out, int out_size, void* d_ws, size_t ws_size,
                              hipStream_t stream) {
    (void)in_sizes; (void)n_in; (void)out_size; (void)ws_size;
    const float* Wn    = (const float*)d_in[0];
    const int*   signs = (const int*)d_in[1];
    const float* x0    = (const float*)d_in[2];
    const float* y0    = (const float*)d_in[3];
    const float* Wi    = (const float*)d_in[4];
    const float* bi    = (const float*)d_in[5];
    const float* Wh1   = (const float*)d_in[6];
    const float* bh1   = (const float*)d_in[7];
    const float* Wh2   = (const float*)d_in[8];
    const float* bh2   = (const float*)d_in[9];
    const float* Wo    = (const float*)d_in[10];
    const float* bo    = (const float*)d_in[11];

    float* out  = (float*)d_out;
    float* xout = out;                       // [2048,100]
    float* yout = out + (size_t)B_SZ * DX;   // [2048,1]

    const size_t NROWS = (size_t)B_SZ * NSTEP * 2;           // 524288
    char* ws = (char*)d_ws;
    size_t off = 0;
    bf16*  U      = (bf16*)(ws + off); off += NROWS * UCOLS * sizeof(bf16);   // ~109 MB
    float* incr   = (float*)(ws + off); off += (NROWS / 2) * sizeof(float);   // 1 MB
    bf16*  wfWi   = (bf16*)(ws + off); off += 32768 * sizeof(bf16);
    bf16*  wfWh1  = (bf16*)(ws + off); off += 65536 * sizeof(bf16);
    bf16*  wfWh2  = (bf16*)(ws + off); off += 65536 * sizeof(bf16);
    bf16*  wfWo   = (bf16*)(ws + off); off += 32768 * sizeof(bf16);
    float* biases = (float*)(ws + off); off += 896 * sizeof(float);

    prep_kernel<<<B_SZ, 128, 0, stream>>>(Wn, signs, x0, U, xout);
    // c-major frag layout: NTILE = output tiles, KC chunks derived from total
    wpack_kernel<<<128, 256, 0, stream>>>(Wi,  wfWi,  101, 256, 16, 32768);
    wpack_kernel<<<256, 256, 0, stream>>>(Wh1, wfWh1, 256, 256, 16, 65536);
    wpack_kernel<<<256, 256, 0, stream>>>(Wh2, wfWh2, 256, 256, 16, 65536);
    wpack_kernel<<<128, 256, 0, stream>>>(Wo,  wfWo,  256, 100, 8,  32768);
    bpack_kernel<<<4, 256, 0, stream>>>(bi, bh1, bh2, bo, biases);

    mlp_mfma_kernel<<<(int)(NROWS / 128), 256, 0, stream>>>(
        U, Wn, signs, wfWi, wfWh1, wfWh2, wfWo, biases, incr);
    y_kernel<<<B_SZ, 128, 0, stream>>>(incr, y0, yout);
}

// Round 6
// 417.859 us; speedup vs baseline: 1.2168x; 1.2168x over previous
//
#include <hip/hip_runtime.h>
#include <hip/hip_bf16.h>

typedef __hip_bfloat16 bf16;
typedef __attribute__((ext_vector_type(8))) short bf16x8v;   // 8 bf16 (4 VGPRs) MFMA operand
typedef __attribute__((ext_vector_type(4))) float f32x4;     // MFMA accumulator
typedef __attribute__((ext_vector_type(4))) short short4v;   // 8B packed bf16 store

#define B_SZ   2048
#define NSTEP  128
#define DD     100
#define DX     100
#define DH     256

#define UCOLS  104          // 100 x-dims + t + 3 zero pad (global U layout)

__device__ __constant__ const float DT_   = 0.0078125f;              // 1/128
__device__ __constant__ const float SQDT_ = 0.08838834764831845f;    // sqrt(1/128)
// sqrt(2)*sqrt(dt) = sqrt(2/128) = 1/8 exactly
__device__ __constant__ const float C1_   = 0.125f;

// ---------------------------------------------------------------------------
// Kernel 1: per-batch prefix sums of noise -> build U rows (bf16) + final x
// U row p = (b*128 + i)*2 + h ; cols 0..99 = x-part, col 100 = t, 101..103 = 0
// ---------------------------------------------------------------------------
__global__ __launch_bounds__(128) void prep_kernel(
    const float* __restrict__ Wn, const int* __restrict__ signs,
    const float* __restrict__ x0,
    bf16* __restrict__ U, float* __restrict__ xout)
{
    __shared__ float w_l[DD * 129];   // padded stride 129 -> conflict-free
    __shared__ float s_l[NSTEP];
    const int b = blockIdx.x, tid = threadIdx.x;
    const float* wb = Wn + (size_t)b * DD * NSTEP;

    for (int idx = tid; idx < DD * NSTEP; idx += 128) {
        int d = idx >> 7, i = idx & 127;
        w_l[d * 129 + i] = wb[idx];
    }
    if (tid < NSTEP) s_l[tid] = 2.f * (float)signs[tid] - 1.f;
    __syncthreads();

    if (tid < DD) {
        const int d = tid;
        float x = x0[d];
        for (int i = 0; i < NSTEP; ++i) {
            size_t p = ((size_t)(b * NSTEP + i)) * 2;
            float wn = w_l[d * 129 + i];
            U[p * UCOLS + d]       = __float2bfloat16(x);
            U[(p + 1) * UCOLS + d] = __float2bfloat16(x + C1_ * (wn - s_l[i]));
            x += C1_ * wn;
        }
        xout[(size_t)b * DX + d] = x;   // exact f32 final x
    } else if (tid < UCOLS) {
        for (int i = 0; i < NSTEP; ++i) {
            size_t p = ((size_t)(b * NSTEP + i)) * 2;
            float v0 = 0.f, v1 = 0.f;
            if (tid == 100) { v0 = DT_ * (float)i; v1 = DT_ * (float)(i + 1); }
            U[p * UCOLS + tid]       = __float2bfloat16(v0);
            U[(p + 1) * UCOLS + tid] = __float2bfloat16(v1);
        }
    }
}

// ---------------------------------------------------------------------------
// Weight fragment packing: W[Kact][Nact] f32 -> bf16 A-frags of W^T, C-MAJOR:
// frag# = c*NTILE + t  (all n-tiles of one k-chunk contiguous -> per-c a-loads
// span one compact window; proven spill-free addressing in R5).
// elem idx = frag#*512 + lane*8 + j. n = t*16+(lane&15), k = c*32+(lane>>4)*8+j.
// OOR -> 0 (handles K=101->128 and N=100->128 padding).
// ---------------------------------------------------------------------------
__global__ __launch_bounds__(256) void wpack_kernel(
    const float* __restrict__ W, bf16* __restrict__ dst,
    int Kact, int Nact, int NTILE, int total)
{
    int idx = blockIdx.x * 256 + threadIdx.x;
    if (idx >= total) return;
    int j = idx & 7;
    int l = (idx >> 3) & 63;
    int frag = idx >> 9;
    int t = frag % NTILE;
    int c = frag / NTILE;
    int n = t * 16 + (l & 15);
    int k = c * 32 + (l >> 4) * 8 + j;
    float v = (k < Kact && n < Nact) ? W[(size_t)k * Nact + n] : 0.f;
    dst[idx] = __float2bfloat16(v);
}

// Pack biases into one padded f32 buffer: [0:256)=bi [256:512)=bh1 [512:768)=bh2 [768:896)=bo(pad0)
__global__ __launch_bounds__(256) void bpack_kernel(
    const float* __restrict__ bi, const float* __restrict__ bh1,
    const float* __restrict__ bh2, const float* __restrict__ bo,
    float* __restrict__ dst)
{
    int i = blockIdx.x * 256 + threadIdx.x;
    if (i < 256) dst[i] = bi[i];
    else if (i < 512) dst[i] = bh1[i - 256];
    else if (i < 768) dst[i] = bh2[i - 512];
    else if (i < 896) dst[i] = (i - 768 < DD) ? bo[i - 768] : 0.f;
}

// ---------------------------------------------------------------------------
// One MFMA layer, 2x2 wave decomposition, IN PLACE in one LDS buffer:
// wave (wm,wn) computes features [(t0)*16, (t0+NT)*16) for rows [m0, m0+MT*16).
// - act b-frags: each read by only the 2 waves of the wm row-group (2x, vs 4x
//   in the R3 all-m structure) -> act-LDS traffic and conflicts ~halve (R4
//   measured the conflict halving).
// - weight a-frags: c-major global layout, one load per (c,t) from a compact
//   per-c window; the wm-pair convoys through the same addresses -> L1 hits.
//   (R5 proved this addressing is spill-free at VGPR=96.)
//   phase 1: accumulate into regs (reads buf)  -> __syncthreads
//   phase 2: bias+relu+pack, store back to buf
// Caller must __syncthreads() after return before the next layer reads.
// ---------------------------------------------------------------------------
template<int KC, int NTT, int NT, int MT, bool RELU>
__device__ __forceinline__ void layer_2x2(
    char* __restrict__ buf,
    const bf16* __restrict__ wfrag, const float* __restrict__ bias,
    int lane, int m0, int t0)
{
    const int lrow = lane & 15;   // m_local (B col) / n_local (A row)
    const int lkg  = lane >> 4;   // k-group
    f32x4 acc[NT][MT];
#pragma unroll
    for (int t = 0; t < NT; ++t)
#pragma unroll
        for (int mt = 0; mt < MT; ++mt) acc[t][mt] = (f32x4){0.f, 0.f, 0.f, 0.f};

    const char* wptr = (const char*)wfrag + (size_t)t0 * 1024 + (size_t)lane * 16;

#pragma unroll 2
    for (int c = 0; c < KC; ++c) {
        bf16x8v b[MT];
#pragma unroll
        for (int mt = 0; mt < MT; ++mt) {
            int m = m0 + mt * 16 + lrow;
            b[mt] = *(const bf16x8v*)(buf + m * 512 +
                                      ((c * 64 + lkg * 16) ^ ((m & 7) << 4)));
        }
        __builtin_amdgcn_s_setprio(1);
#pragma unroll
        for (int t = 0; t < NT; ++t) {
            bf16x8v a = *(const bf16x8v*)(wptr + (size_t)(c * NTT + t) * 1024);
#pragma unroll
            for (int mt = 0; mt < MT; ++mt)
                acc[t][mt] = __builtin_amdgcn_mfma_f32_16x16x32_bf16(a, b[mt], acc[t][mt], 0, 0, 0);
        }
        __builtin_amdgcn_s_setprio(0);
    }

    __syncthreads();   // all reads of buf complete block-wide; safe to overwrite

#pragma unroll
    for (int t = 0; t < NT; ++t) {
        const int nb = (t0 + t) * 16 + lkg * 4;   // first of 4 consecutive features
        const float4 bv = *(const float4*)(bias + nb);
#pragma unroll
        for (int mt = 0; mt < MT; ++mt) {
            const int m = m0 + mt * 16 + lrow;
            float v0 = acc[t][mt][0] + bv.x;
            float v1 = acc[t][mt][1] + bv.y;
            float v2 = acc[t][mt][2] + bv.z;
            float v3 = acc[t][mt][3] + bv.w;
            if (RELU) {
                v0 = fmaxf(v0, 0.f); v1 = fmaxf(v1, 0.f);
                v2 = fmaxf(v2, 0.f); v3 = fmaxf(v3, 0.f);
            }
            bf16 h0 = __float2bfloat16(v0), h1 = __float2bfloat16(v1);
            bf16 h2 = __float2bfloat16(v2), h3 = __float2bfloat16(v3);
            short4v pv;
            pv[0] = *(short*)&h0; pv[1] = *(short*)&h1;
            pv[2] = *(short*)&h2; pv[3] = *(short*)&h3;
            *(short4v*)(buf + m * 512 + ((nb * 2) ^ ((m & 7) << 4))) = pv;
        }
    }
}

// ---------------------------------------------------------------------------
// Kernel 2: fused 4-layer MFMA MLP over 128 rows + per-pair y-increment.
// 4 waves as 2x2: wm -> rows [wm*64,+64), wn -> feature half [wn*128,+128).
// acc[8][4]=128 AGPRs + ~96 arch VGPRs (R5-proven) -> ~224 < 256 cap at
// (256,2): no spill (tripwire: WRITE_SIZE must stay ~1MB).
// buf [128][512B] swizzled, 64KB -> 2 blocks/CU.
// ---------------------------------------------------------------------------
__global__ __launch_bounds__(256, 2) void mlp_mfma_kernel(
    const bf16* __restrict__ U,
    const float* __restrict__ Wn, const int* __restrict__ signs,
    const bf16* __restrict__ wfWi, const bf16* __restrict__ wfWh1,
    const bf16* __restrict__ wfWh2, const bf16* __restrict__ wfWo,
    const float* __restrict__ biases, float* __restrict__ incr)
{
    __shared__ char buf[128 * 512];
    __shared__ float Sz2[128], Szw[128];
    const int tid = threadIdx.x;
    const int lane = tid & 63, w = tid >> 6;
    const int wm = w >> 1, wn = w & 1;
    const int m0 = wm * 64;
    const size_t row0 = (size_t)blockIdx.x * 128;

    // Load U tile: 128 rows x 104 bf16 = 13 x 16B chunks/row -> buf [128][512B]
    // (layer-1 input occupies bytes 0..255), swizzled; chunks 13..15 zero-filled
    // (k padding must be 0).
    {
        const char* usrc = (const char*)(U + row0 * UCOLS);
        for (int idx = tid; idx < 2048; idx += 256) {
            int r = idx >> 4, c = idx & 15;
            uint4 v = (uint4){0, 0, 0, 0};
            if (c < 13) v = *(const uint4*)(usrc + r * 208 + c * 16);
            *(uint4*)(buf + r * 512 + ((c * 16) ^ ((r & 7) << 4))) = v;
        }
    }
    __syncthreads();

    layer_2x2<4, 16, 8, 4, true >(buf, wfWi,  biases,        lane, m0, wn * 8);
    __syncthreads();
    layer_2x2<8, 16, 8, 4, true >(buf, wfWh1, biases + 256,  lane, m0, wn * 8);
    __syncthreads();
    layer_2x2<8, 16, 8, 4, true >(buf, wfWh2, biases + 512,  lane, m0, wn * 8);
    __syncthreads();
    layer_2x2<8, 8,  4, 4, false>(buf, wfWo,  biases + 768,  lane, m0, wn * 4);
    __syncthreads();
    // z rows now in buf [128][512B] (features 0..99 valid)

    // Per-row reductions: 4 threads per row, two passes of 64 rows
    const int q = tid & 3;
#pragma unroll
    for (int half = 0; half < 2; ++half) {
        const int r = (tid >> 2) + half * 64;
        const size_t g = row0 + r;
        const size_t pair = g >> 1;
        const int h = (int)(g & 1);
        const int bb = (int)(pair >> 7), ii = (int)(pair & 127);
        const float s = 2.f * (float)signs[ii] - 1.f;
        const float sdt = s * SQDT_;
        const float* wb = Wn + (size_t)bb * DD * NSTEP + ii;

        float sz2 = 0.f, szw = 0.f;
        for (int d = q; d < DD; d += 4) {
            unsigned short zb = *(const unsigned short*)(buf + r * 512 + ((d * 2) ^ ((r & 7) << 4)));
            union { unsigned int u; float f; } cv; cv.u = ((unsigned int)zb) << 16;
            float z = cv.f;
            float wv = SQDT_ * wb[(size_t)d * NSTEP];
            float wt = h ? (wv + sdt) : (wv - sdt);
            sz2 += z * z;
            szw += z * wt;
        }
        sz2 += __shfl_xor(sz2, 1); sz2 += __shfl_xor(sz2, 2);
        szw += __shfl_xor(szw, 1); szw += __shfl_xor(szw, 2);
        if (q == 0) { Sz2[r] = sz2; Szw[r] = szw; }
    }
    __syncthreads();

    // incr = -||z||^2*dt + 0.5*(z.(w-sdt) + z_new.(w+sdt));  z from h=0 row
    if (tid < 64) {
        int rr = tid * 2;
        incr[row0 / 2 + tid] = -Sz2[rr] * DT_ + 0.5f * (Szw[rr] + Szw[rr + 1]);
    }
}

// ---------------------------------------------------------------------------
// Kernel 3: y[b] = y0 + sum_i incr[b*128+i]
// ---------------------------------------------------------------------------
__global__ __launch_bounds__(128) void y_kernel(
    const float* __restrict__ incr, const float* __restrict__ y0,
    float* __restrict__ yout)
{
    const int b = blockIdx.x, tid = threadIdx.x;
    float v = incr[(size_t)b * NSTEP + tid];
#pragma unroll
    for (int off = 1; off < 64; off <<= 1) v += __shfl_xor(v, off);
    __shared__ float partial[2];
    if ((tid & 63) == 0) partial[tid >> 6] = v;
    __syncthreads();
    if (tid == 0) yout[b] = y0[0] + partial[0] + partial[1];
}

// ---------------------------------------------------------------------------
extern "C" void kernel_launch(void* const* d_in, const int* in_sizes, int n_in,
                              void* d_out, int out_size, void* d_ws, size_t ws_size,
                              hipStream_t stream) {
    (void)in_sizes; (void)n_in; (void)out_size; (void)ws_size;
    const float* Wn    = (const float*)d_in[0];
    const int*   signs = (const int*)d_in[1];
    const float* x0    = (const float*)d_in[2];
    const float* y0    = (const float*)d_in[3];
    const float* Wi    = (const float*)d_in[4];
    const float* bi    = (const float*)d_in[5];
    const float* Wh1   = (const float*)d_in[6];
    const float* bh1   = (const float*)d_in[7];
    const float* Wh2   = (const float*)d_in[8];
    const float* bh2   = (const float*)d_in[9];
    const float* Wo    = (const float*)d_in[10];
    const float* bo    = (const float*)d_in[11];

    float* out  = (float*)d_out;
    float* xout = out;                       // [2048,100]
    float* yout = out + (size_t)B_SZ * DX;   // [2048,1]

    const size_t NROWS = (size_t)B_SZ * NSTEP * 2;           // 524288
    char* ws = (char*)d_ws;
    size_t off = 0;
    bf16*  U      = (bf16*)(ws + off); off += NROWS * UCOLS * sizeof(bf16);   // ~109 MB
    float* incr   = (float*)(ws + off); off += (NROWS / 2) * sizeof(float);   // 1 MB
    bf16*  wfWi   = (bf16*)(ws + off); off += 32768 * sizeof(bf16);
    bf16*  wfWh1  = (bf16*)(ws + off); off += 65536 * sizeof(bf16);
    bf16*  wfWh2  = (bf16*)(ws + off); off += 65536 * sizeof(bf16);
    bf16*  wfWo   = (bf16*)(ws + off); off += 32768 * sizeof(bf16);
    float* biases = (float*)(ws + off); off += 896 * sizeof(float);

    prep_kernel<<<B_SZ, 128, 0, stream>>>(Wn, signs, x0, U, xout);
    // c-major frag layout: NTILE = total n-tiles per layer
    wpack_kernel<<<128, 256, 0, stream>>>(Wi,  wfWi,  101, 256, 16, 32768);
    wpack_kernel<<<256, 256, 0, stream>>>(Wh1, wfWh1, 256, 256, 16, 65536);
    wpack_kernel<<<256, 256, 0, stream>>>(Wh2, wfWh2, 256, 256, 16, 65536);
    wpack_kernel<<<128, 256, 0, stream>>>(Wo,  wfWo,  256, 100, 8,  32768);
    bpack_kernel<<<4, 256, 0, stream>>>(bi, bh1, bh2, bo, biases);

    mlp_mfma_kernel<<<(int)(NROWS / 128), 256, 0, stream>>>(
        U, Wn, signs, wfWi, wfWh1, wfWh2, wfWo, biases, incr);
    y_kernel<<<B_SZ, 128, 0, stream>>>(incr, y0, yout);
}

// Round 7
// 326.438 us; speedup vs baseline: 1.5575x; 1.2801x over previous
//
#include <hip/hip_runtime.h>
#include <hip/hip_bf16.h>

typedef __hip_bfloat16 bf16;
typedef __attribute__((ext_vector_type(8)))  short bf16x8v;  // 8 bf16 (4 VGPRs) MFMA operand
typedef __attribute__((ext_vector_type(16))) float f32x16;   // 32x32 MFMA accumulator
typedef __attribute__((ext_vector_type(4)))  short short4v;  // 8B packed bf16 store

#define B_SZ   2048
#define NSTEP  128
#define DD     100
#define DX     100
#define DH     256

#define UCOLS  104          // 100 x-dims + t + 3 zero pad (global U layout)

__device__ __constant__ const float DT_   = 0.0078125f;              // 1/128
__device__ __constant__ const float SQDT_ = 0.08838834764831845f;    // sqrt(1/128)
// sqrt(2)*sqrt(dt) = sqrt(2/128) = 1/8 exactly
__device__ __constant__ const float C1_   = 0.125f;

// ---------------------------------------------------------------------------
// Kernel 1: per-batch prefix sums of noise -> build U rows (bf16) + final x
// U row p = (b*128 + i)*2 + h ; cols 0..99 = x-part, col 100 = t, 101..103 = 0
// ---------------------------------------------------------------------------
__global__ __launch_bounds__(128) void prep_kernel(
    const float* __restrict__ Wn, const int* __restrict__ signs,
    const float* __restrict__ x0,
    bf16* __restrict__ U, float* __restrict__ xout)
{
    __shared__ float w_l[DD * 129];   // padded stride 129 -> conflict-free
    __shared__ float s_l[NSTEP];
    const int b = blockIdx.x, tid = threadIdx.x;
    const float* wb = Wn + (size_t)b * DD * NSTEP;

    for (int idx = tid; idx < DD * NSTEP; idx += 128) {
        int d = idx >> 7, i = idx & 127;
        w_l[d * 129 + i] = wb[idx];
    }
    if (tid < NSTEP) s_l[tid] = 2.f * (float)signs[tid] - 1.f;
    __syncthreads();

    if (tid < DD) {
        const int d = tid;
        float x = x0[d];
        for (int i = 0; i < NSTEP; ++i) {
            size_t p = ((size_t)(b * NSTEP + i)) * 2;
            float wn = w_l[d * 129 + i];
            U[p * UCOLS + d]       = __float2bfloat16(x);
            U[(p + 1) * UCOLS + d] = __float2bfloat16(x + C1_ * (wn - s_l[i]));
            x += C1_ * wn;
        }
        xout[(size_t)b * DX + d] = x;   // exact f32 final x
    } else if (tid < UCOLS) {
        for (int i = 0; i < NSTEP; ++i) {
            size_t p = ((size_t)(b * NSTEP + i)) * 2;
            float v0 = 0.f, v1 = 0.f;
            if (tid == 100) { v0 = DT_ * (float)i; v1 = DT_ * (float)(i + 1); }
            U[p * UCOLS + tid]       = __float2bfloat16(v0);
            U[(p + 1) * UCOLS + tid] = __float2bfloat16(v1);
        }
    }
}

// ---------------------------------------------------------------------------
// Weight fragment packing for 32x32x16 MFMA: W[Kact][Nact] f32 -> bf16 A-frags
// of W^T, C-MAJOR: frag# = c*NTILE + t (per-c window contiguous; spill-free
// addressing proven in R5/R6). elem idx = frag#*512 + lane*8 + j.
// n = t*32 + (lane&31), k = c*16 + (lane>>5)*8 + j. OOR -> 0.
// ---------------------------------------------------------------------------
__global__ __launch_bounds__(256) void wpack_kernel(
    const float* __restrict__ W, bf16* __restrict__ dst,
    int Kact, int Nact, int NTILE, int total)
{
    int idx = blockIdx.x * 256 + threadIdx.x;
    if (idx >= total) return;
    int j = idx & 7;
    int l = (idx >> 3) & 63;
    int frag = idx >> 9;
    int t = frag % NTILE;
    int c = frag / NTILE;
    int n = t * 32 + (l & 31);
    int k = c * 16 + (l >> 5) * 8 + j;
    float v = (k < Kact && n < Nact) ? W[(size_t)k * Nact + n] : 0.f;
    dst[idx] = __float2bfloat16(v);
}

// Pack biases into one padded f32 buffer: [0:256)=bi [256:512)=bh1 [512:768)=bh2 [768:896)=bo(pad0)
__global__ __launch_bounds__(256) void bpack_kernel(
    const float* __restrict__ bi, const float* __restrict__ bh1,
    const float* __restrict__ bh2, const float* __restrict__ bo,
    float* __restrict__ dst)
{
    int i = blockIdx.x * 256 + threadIdx.x;
    if (i < 256) dst[i] = bi[i];
    else if (i < 512) dst[i] = bh1[i - 256];
    else if (i < 768) dst[i] = bh2[i - 512];
    else if (i < 896) dst[i] = (i - 768 < DD) ? bo[i - 768] : 0.f;
}

// ---------------------------------------------------------------------------
// One 32x32x16-MFMA layer, IN PLACE, 64-row tile, 4-way n-split (R3-winning
// decomposition: weights 1x per block, act 4x from LDS).
// Wave w owns NT n-tiles of 32 feats at t0; all 64 rows (MT=2 m-tiles of 32).
// Per c-iter (k=16): 2 ds_read_b128 (b), NT global a-loads, 2*NT MFMAs.
// vs 16x16 R3: instruction counts halved at same bytes; 32x32 pipe ~15%
// faster per FLOP. acc = NT*2 f32x16 = 64 regs (NT=2) -> fits (256,4).
//   phase 1: accumulate into regs -> __syncthreads
//   phase 2: bias+relu+pack, store back to buf
// Caller must __syncthreads() after return before the next layer reads.
// Swizzle: byte ^= (m&15)<<4 (16 slots -> write/read BW-floor, bijective
// within each 256B half-row since col-bits 4..7 are flipped).
// ---------------------------------------------------------------------------
template<int KC, int NTT, int NT, bool RELU>
__device__ __forceinline__ void layer32(
    char* __restrict__ buf,
    const bf16* __restrict__ wfrag, const float* __restrict__ bias,
    int lane, int t0)
{
    const int mrow = lane & 31;   // m within tile (B col)
    const int kg   = lane >> 5;   // k-group (0/1)
    f32x16 acc[NT][2];
#pragma unroll
    for (int t = 0; t < NT; ++t) {
#pragma unroll
        for (int mt = 0; mt < 2; ++mt)
#pragma unroll
            for (int e = 0; e < 16; ++e) acc[t][mt][e] = 0.f;
    }

    const char* wptr = (const char*)wfrag + (size_t)t0 * 1024 + (size_t)lane * 16;

#pragma unroll 2
    for (int c = 0; c < KC; ++c) {
        const int col = c * 32 + kg * 16;
        const int ma = mrow;          // tile 0: rows 0..31
        const int mb = 32 + mrow;     // tile 1: rows 32..63
        bf16x8v b0 = *(const bf16x8v*)(buf + ma * 512 + (col ^ ((ma & 15) << 4)));
        bf16x8v b1 = *(const bf16x8v*)(buf + mb * 512 + (col ^ ((mb & 15) << 4)));
        __builtin_amdgcn_s_setprio(1);
#pragma unroll
        for (int t = 0; t < NT; ++t) {
            bf16x8v a = *(const bf16x8v*)(wptr + (size_t)(c * NTT + t) * 1024);
            acc[t][0] = __builtin_amdgcn_mfma_f32_32x32x16_bf16(a, b0, acc[t][0], 0, 0, 0);
            acc[t][1] = __builtin_amdgcn_mfma_f32_32x32x16_bf16(a, b1, acc[t][1], 0, 0, 0);
        }
        __builtin_amdgcn_s_setprio(0);
    }

    __syncthreads();   // all reads of buf complete block-wide; safe to overwrite

    // C/D layout 32x32: col(m) = lane&31, row(n) = (r&3) + 8*(r>>2) + 4*kg
#pragma unroll
    for (int t = 0; t < NT; ++t) {
#pragma unroll
        for (int g = 0; g < 4; ++g) {
            const int nb = (t0 + t) * 32 + g * 8 + kg * 4;  // 4 consecutive features
            const float4 bv = *(const float4*)(bias + nb);
#pragma unroll
            for (int mt = 0; mt < 2; ++mt) {
                const int m = mt * 32 + mrow;
                float v0 = acc[t][mt][g * 4 + 0] + bv.x;
                float v1 = acc[t][mt][g * 4 + 1] + bv.y;
                float v2 = acc[t][mt][g * 4 + 2] + bv.z;
                float v3 = acc[t][mt][g * 4 + 3] + bv.w;
                if (RELU) {
                    v0 = fmaxf(v0, 0.f); v1 = fmaxf(v1, 0.f);
                    v2 = fmaxf(v2, 0.f); v3 = fmaxf(v3, 0.f);
                }
                bf16 h0 = __float2bfloat16(v0), h1 = __float2bfloat16(v1);
                bf16 h2 = __float2bfloat16(v2), h3 = __float2bfloat16(v3);
                short4v pv;
                pv[0] = *(short*)&h0; pv[1] = *(short*)&h1;
                pv[2] = *(short*)&h2; pv[3] = *(short*)&h3;
                *(short4v*)(buf + m * 512 + ((nb * 2) ^ ((m & 15) << 4))) = pv;
            }
        }
    }
}

// ---------------------------------------------------------------------------
// Kernel 2: fused 4-layer 32x32-MFMA MLP over 64 rows + per-pair y-increment.
// 4 waves n-split (weights 1x/block). acc 64 + arch ~45 regs -> (256,4)
// should NOT spill (tripwire: WRITE_SIZE ~1MB, VGPR<=128).
// buf 64x512B = 32KB -> 33280B LDS -> 4 blocks/CU at 4 waves/SIMD.
// ---------------------------------------------------------------------------
__global__ __launch_bounds__(256, 4) void mlp_mfma_kernel(
    const bf16* __restrict__ U,
    const float* __restrict__ Wn, const int* __restrict__ signs,
    const bf16* __restrict__ wfWi, const bf16* __restrict__ wfWh1,
    const bf16* __restrict__ wfWh2, const bf16* __restrict__ wfWo,
    const float* __restrict__ biases, float* __restrict__ incr)
{
    __shared__ char buf[64 * 512];
    __shared__ float Sz2[64], Szw[64];
    const int tid = threadIdx.x;
    const int lane = tid & 63, w = tid >> 6;
    const size_t row0 = (size_t)blockIdx.x * 64;

    // Load U tile: 64 rows x 104 bf16 = 13 x 16B chunks/row -> buf [64][512B]
    // (layer-1 input occupies bytes 0..207, zero-fill to 255), swizzled.
    {
        const char* usrc = (const char*)(U + row0 * UCOLS);
        for (int idx = tid; idx < 1024; idx += 256) {
            int r = idx >> 4, c = idx & 15;
            uint4 v = (uint4){0, 0, 0, 0};
            if (c < 13) v = *(const uint4*)(usrc + r * 208 + c * 16);
            *(uint4*)(buf + r * 512 + ((c * 16) ^ ((r & 15) << 4))) = v;
        }
    }
    __syncthreads();

    layer32<7,  8, 2, true >(buf, wfWi,  biases,        lane, w * 2);
    __syncthreads();
    layer32<16, 8, 2, true >(buf, wfWh1, biases + 256,  lane, w * 2);
    __syncthreads();
    layer32<16, 8, 2, true >(buf, wfWh2, biases + 512,  lane, w * 2);
    __syncthreads();
    layer32<16, 4, 1, false>(buf, wfWo,  biases + 768,  lane, w);
    __syncthreads();
    // z rows now in buf [64][512B] (features 0..99 valid)

    // Per-row reductions: 4 threads per row
    const int r = tid >> 2, q = tid & 3;
    const size_t g = row0 + r;
    const size_t pair = g >> 1;
    const int h = (int)(g & 1);
    const int bb = (int)(pair >> 7), ii = (int)(pair & 127);
    const float s = 2.f * (float)signs[ii] - 1.f;
    const float sdt = s * SQDT_;
    const float* wb = Wn + (size_t)bb * DD * NSTEP + ii;

    float sz2 = 0.f, szw = 0.f;
    for (int d = q; d < DD; d += 4) {
        unsigned short zb = *(const unsigned short*)(buf + r * 512 + ((d * 2) ^ ((r & 15) << 4)));
        union { unsigned int u; float f; } cv; cv.u = ((unsigned int)zb) << 16;
        float z = cv.f;
        float wv = SQDT_ * wb[(size_t)d * NSTEP];
        float wt = h ? (wv + sdt) : (wv - sdt);
        sz2 += z * z;
        szw += z * wt;
    }
    sz2 += __shfl_xor(sz2, 1); sz2 += __shfl_xor(sz2, 2);
    szw += __shfl_xor(szw, 1); szw += __shfl_xor(szw, 2);
    if (q == 0) { Sz2[r] = sz2; Szw[r] = szw; }
    __syncthreads();

    // incr = -||z||^2*dt + 0.5*(z.(w-sdt) + z_new.(w+sdt));  z from h=0 row
    if (tid < 32) {
        int rr = tid * 2;
        incr[row0 / 2 + tid] = -Sz2[rr] * DT_ + 0.5f * (Szw[rr] + Szw[rr + 1]);
    }
}

// ---------------------------------------------------------------------------
// Kernel 3: y[b] = y0 + sum_i incr[b*128+i]
// ---------------------------------------------------------------------------
__global__ __launch_bounds__(128) void y_kernel(
    const float* __restrict__ incr, const float* __restrict__ y0,
    float* __restrict__ yout)
{
    const int b = blockIdx.x, tid = threadIdx.x;
    float v = incr[(size_t)b * NSTEP + tid];
#pragma unroll
    for (int off = 1; off < 64; off <<= 1) v += __shfl_xor(v, off);
    __shared__ float partial[2];
    if ((tid & 63) == 0) partial[tid >> 6] = v;
    __syncthreads();
    if (tid == 0) yout[b] = y0[0] + partial[0] + partial[1];
}

// ---------------------------------------------------------------------------
extern "C" void kernel_launch(void* const* d_in, const int* in_sizes, int n_in,
                              void* d_out, int out_size, void* d_ws, size_t ws_size,
                              hipStream_t stream) {
    (void)in_sizes; (void)n_in; (void)out_size; (void)ws_size;
    const float* Wn    = (const float*)d_in[0];
    const int*   signs = (const int*)d_in[1];
    const float* x0    = (const float*)d_in[2];
    const float* y0    = (const float*)d_in[3];
    const float* Wi    = (const float*)d_in[4];
    const float* bi    = (const float*)d_in[5];
    const float* Wh1   = (const float*)d_in[6];
    const float* bh1   = (const float*)d_in[7];
    const float* Wh2   = (const float*)d_in[8];
    const float* bh2   = (const float*)d_in[9];
    const float* Wo    = (const float*)d_in[10];
    const float* bo    = (const float*)d_in[11];

    float* out  = (float*)d_out;
    float* xout = out;                       // [2048,100]
    float* yout = out + (size_t)B_SZ * DX;   // [2048,1]

    const size_t NROWS = (size_t)B_SZ * NSTEP * 2;           // 524288
    char* ws = (char*)d_ws;
    size_t off = 0;
    bf16*  U      = (bf16*)(ws + off); off += NROWS * UCOLS * sizeof(bf16);   // ~109 MB
    float* incr   = (float*)(ws + off); off += (NROWS / 2) * sizeof(float);   // 1 MB
    bf16*  wfWi   = (bf16*)(ws + off); off += 28672 * sizeof(bf16);   // KC=7,  8 tiles
    bf16*  wfWh1  = (bf16*)(ws + off); off += 65536 * sizeof(bf16);   // KC=16, 8 tiles
    bf16*  wfWh2  = (bf16*)(ws + off); off += 65536 * sizeof(bf16);
    bf16*  wfWo   = (bf16*)(ws + off); off += 32768 * sizeof(bf16);   // KC=16, 4 tiles
    float* biases = (float*)(ws + off); off += 896 * sizeof(float);

    prep_kernel<<<B_SZ, 128, 0, stream>>>(Wn, signs, x0, U, xout);
    // c-major 32x32 frag layout: NTILE = n-tiles of 32
    wpack_kernel<<<112, 256, 0, stream>>>(Wi,  wfWi,  101, 256, 8, 28672);
    wpack_kernel<<<256, 256, 0, stream>>>(Wh1, wfWh1, 256, 256, 8, 65536);
    wpack_kernel<<<256, 256, 0, stream>>>(Wh2, wfWh2, 256, 256, 8, 65536);
    wpack_kernel<<<128, 256, 0, stream>>>(Wo,  wfWo,  256, 100, 4, 32768);
    bpack_kernel<<<4, 256, 0, stream>>>(bi, bh1, bh2, bo, biases);

    mlp_mfma_kernel<<<(int)(NROWS / 64), 256, 0, stream>>>(
        U, Wn, signs, wfWi, wfWh1, wfWh2, wfWo, biases, incr);
    y_kernel<<<B_SZ, 128, 0, stream>>>(incr, y0, yout);
}